// Round 1
// baseline (359.630 us; speedup 1.0000x reference)
//
#include <hip/hip_runtime.h>

// Overlap-add reconstruction (inverse framing), MI355X / gfx950.
//
// x: [B, FV=2000, FRAME=2048] fp32, HOP=512, PAD0=PAD1=768.
// out[b][o] = (1/cnt) * sum_{f in [max(0,q-3), min(FV-1,q)]} x[b][f][p - 512f]
//   where p = o + PAD0, q = p >> 9, cnt = #valid f (2..4).
//
// Pure gather: each input element is read exactly once (trimmed edges never
// read), each output written once -> memory-bound, ~328 MB total traffic.
//
// float4 vectorization is safe: o % 4 == 0 implies the group p..p+3 stays
// within one 512-sample hop block ((p&511) <= 508), so q/cnt are uniform
// per group and every frame access is a 16B-aligned float4 load.

#define FRAME   2048
#define HOP     512
#define NFV     2000
#define PAD0    768
#define OUT_PER_B (NFV * HOP)          // 1,024,000
#define IN_PER_B  (NFV * FRAME)        // 4,096,000
#define BLOCK   256

__global__ __launch_bounds__(BLOCK) void ola_gather_kernel(
    const float* __restrict__ x, float* __restrict__ out)
{
    const int b = blockIdx.y;
    const int o = (blockIdx.x * BLOCK + threadIdx.x) * 4;   // grid sized exactly
    const int p = o + PAD0;
    const int q = p >> 9;                                    // p / HOP

    const float* xb = x + (size_t)b * IN_PER_B;

    float4 acc = make_float4(0.f, 0.f, 0.f, 0.f);
    int cnt = 0;
#pragma unroll
    for (int j = 0; j < 4; ++j) {
        const int f = q - j;
        if (f >= 0 && f < NFV) {
            const int t = p - (f << 9);                      // in [0, FRAME)
            const float4 v =
                *reinterpret_cast<const float4*>(xb + (size_t)f * FRAME + t);
            acc.x += v.x; acc.y += v.y; acc.z += v.z; acc.w += v.w;
            ++cnt;
        }
    }
    const float s = 1.0f / (float)cnt;
    float4 r = make_float4(acc.x * s, acc.y * s, acc.z * s, acc.w * s);
    *reinterpret_cast<float4*>(out + (size_t)b * OUT_PER_B + o) = r;
}

extern "C" void kernel_launch(void* const* d_in, const int* in_sizes, int n_in,
                              void* d_out, int out_size, void* d_ws, size_t ws_size,
                              hipStream_t stream)
{
    const float* x = (const float*)d_in[0];
    float* out = (float*)d_out;

    const int B = in_sizes[0] / IN_PER_B;                    // 16
    // OUT_PER_B / (BLOCK*4) = 1,024,000 / 1024 = 1000 exactly.
    dim3 grid(OUT_PER_B / (BLOCK * 4), B);
    ola_gather_kernel<<<grid, dim3(BLOCK), 0, stream>>>(x, out);
}

// Round 2
// 345.816 us; speedup vs baseline: 1.0399x; 1.0399x over previous
//
#include <hip/hip_runtime.h>

// Overlap-add reconstruction (inverse framing), MI355X / gfx950. Round 2.
//
// x: [B=16, FV=2000, FRAME=2048] fp32, HOP=512, PAD0=PAD1=768.
// out[b][o] = (1/cnt) * sum_{f in [max(0,q-3), min(FV-1,q)]} x[b][f][p-512f],
//   p = o + PAD0, q = p>>9. Pure gather: each input element read exactly once
//   (FETCH ~256 MB), each output written once (WRITE ~64 MB) -> BW-bound.
//
// R2 changes vs R1:
//  - Block-uniform interior/edge split: each block covers 2048 output samples;
//    only blockIdx.x == 0 and == GRID_X-1 touch the cnt<4 edges. Interior path
//    is 4 unconditional loads + scale 0.25 (no cndmask/cnt chain).
//  - Interior addresses collapse: load j at base - 1536*j floats (one base).
//  - Nontemporal loads/stores: zero reuse on both streams, keep them out of
//    L2/LLC.
//  - 2 float4 groups per thread (coalesced: second group at +BLOCK groups) for
//    more loads in flight per wave; grid (500,16)=8000 blocks still saturates.

#define FRAME   2048
#define HOP     512
#define NFV     2000
#define PAD0    768
#define OUT_PER_B (NFV * HOP)          // 1,024,000
#define IN_PER_B  (NFV * FRAME)        // 4,096,000
#define BLOCK   256
#define ITERS   2
#define GROUPS_PER_BLOCK (BLOCK * ITERS)            // 512 groups = 2048 samples
#define GRID_X  (OUT_PER_B / 4 / GROUPS_PER_BLOCK)  // 256000/512 = 500 exactly

typedef float v4f __attribute__((ext_vector_type(4)));

__global__ __launch_bounds__(BLOCK) void ola_gather_kernel(
    const float* __restrict__ x, float* __restrict__ out)
{
    const int b = blockIdx.y;
    const float* __restrict__ xb = x + (size_t)b * IN_PER_B;
    float* __restrict__ ob = out + (size_t)b * OUT_PER_B;

    int g = blockIdx.x * GROUPS_PER_BLOCK + threadIdx.x;   // float4-group index

    // Block's q range is [4*bx+1, 4*bx+5]; interior needs q>=3 and q<=NFV-1.
    const bool interior = (blockIdx.x >= 1) & (blockIdx.x <= GRID_X - 2);

    if (interior) {
#pragma unroll
        for (int it = 0; it < ITERS; ++it, g += BLOCK) {
            const int o = g * 4;
            const int p = o + PAD0;
            const int q = p >> 9;
            const int r = p & 511;                          // r % 4 == 0
            const float* base = xb + ((size_t)q << 11) + r; // f=q, t=r
            // f = q-j  ->  addr = base - 1536*j
            v4f v0 = __builtin_nontemporal_load((const v4f*)(base));
            v4f v1 = __builtin_nontemporal_load((const v4f*)(base - 1536));
            v4f v2 = __builtin_nontemporal_load((const v4f*)(base - 3072));
            v4f v3 = __builtin_nontemporal_load((const v4f*)(base - 4608));
            v4f s = (v0 + v1 + v2 + v3) * 0.25f;
            __builtin_nontemporal_store(s, (v4f*)(ob + o));
        }
    } else {
        for (int it = 0; it < ITERS; ++it, g += BLOCK) {
            const int o = g * 4;
            const int p = o + PAD0;
            const int q = p >> 9;
            v4f acc = {0.f, 0.f, 0.f, 0.f};
            int cnt = 0;
#pragma unroll
            for (int j = 0; j < 4; ++j) {
                const int f = q - j;
                if (f >= 0 && f < NFV) {
                    const int t = p - (f << 9);
                    const v4f v = *(const v4f*)(xb + (size_t)f * FRAME + t);
                    acc += v;
                    ++cnt;
                }
            }
            const float sc = 1.0f / (float)cnt;
            *(v4f*)(ob + o) = acc * sc;
        }
    }
}

extern "C" void kernel_launch(void* const* d_in, const int* in_sizes, int n_in,
                              void* d_out, int out_size, void* d_ws, size_t ws_size,
                              hipStream_t stream)
{
    const float* x = (const float*)d_in[0];
    float* out = (float*)d_out;

    const int B = in_sizes[0] / IN_PER_B;                   // 16
    dim3 grid(GRID_X, B);
    ola_gather_kernel<<<grid, dim3(BLOCK), 0, stream>>>(x, out);
}